// Round 9
// baseline (380.633 us; speedup 1.0000x reference)
//
#include <hip/hip_runtime.h>
#include <hip/hip_bf16.h>
#include <hip/hip_fp16.h>
#include <math.h>

#define HDIM 128
#define INVD 16
#define DIN 272           // 2*H + INV
#define NKT 9             // K steps of 32 -> 288 (pad 272->288)

typedef __attribute__((ext_vector_type(4))) float f32x4;
typedef __attribute__((ext_vector_type(8))) short bf16x8;
typedef __attribute__((ext_vector_type(2))) __fp16 fp16x2;

__device__ inline short f2bf(float f) {
    union { float f; unsigned u; } v; v.f = f;
    unsigned r = v.u + 0x7FFFu + ((v.u >> 16) & 1u);   // RNE
    return (short)(r >> 16);
}

// ---------------- CSR build (receiver-sorted edge order) ----------------
__global__ void hist_kernel(const int* __restrict__ index, int* __restrict__ cnt, int E) {
    int e = blockIdx.x * blockDim.x + threadIdx.x;
    if (e < E) atomicAdd(&cnt[index[E + e]], 1);
}

__global__ __launch_bounds__(1024) void scan_kernel(const int* __restrict__ cnt,
                                                    int* __restrict__ cur, int N) {
    __shared__ int psum[1024];
    const int t = threadIdx.x;
    const int C = (N + 1023) >> 10;
    const int a0 = t * C;
    const int a1 = (a0 + C < N) ? a0 + C : N;
    int s = 0;
    for (int i = a0; i < a1; ++i) s += cnt[i];
    psum[t] = s;
    __syncthreads();
    for (int d = 1; d < 1024; d <<= 1) {
        int v = (t >= d) ? psum[t - d] : 0;
        __syncthreads();
        psum[t] += v;
        __syncthreads();
    }
    int run = (t > 0) ? psum[t - 1] : 0;
    for (int i = a0; i < a1; ++i) {
        cur[i] = run;
        run += cnt[i];
    }
}

__global__ void fill_kernel(const int* __restrict__ index, int* __restrict__ cur,
                            int* __restrict__ eid, int E) {
    int e = blockIdx.x * blockDim.x + threadIdx.x;
    if (e < E) { int p = atomicAdd(&cur[index[E + e]], 1); eid[p] = e; }
}

// ---------------- main kernel ----------------
// Barrier-free main loop: each wave owns 16 edges x 128 cols.
// W1 (BN-scale folded, bf16) pre-packed in LDS as MFMA B-fragments, read-only.
// MODE 2: receiver-sorted order (eid) + in-register run merge -> pk-f16 atomics
// MODE 1: natural order -> pk-f16 atomics (R8 path)
// MODE 0: natural order -> scalar f32 atomics to out (no-ws fallback)
template<int MODE>
__global__ __launch_bounds__(256, 2) void etnn_kernel(
    const float* __restrict__ x_send,
    const float* __restrict__ x_rec,
    const int*   __restrict__ index,     // [2][E] int32
    const float* __restrict__ edge_attr, // [E][16]
    const float* __restrict__ bn_gamma,
    const float* __restrict__ bn_beta,
    const float* __restrict__ bn_mean,
    const float* __restrict__ bn_var,
    const float* __restrict__ W1,        // [DIN][H]
    const float* __restrict__ b1,
    const float* __restrict__ W2,
    const float* __restrict__ b2,
    const int*   __restrict__ eid,       // [E] sorted edge ids (MODE 2)
    float* __restrict__ out,             // [N][H] (MODE 0)
    __half* __restrict__ ws,             // [N][H] f16 accumulator (MODE 1/2)
    int E, int nIter)
{
    // [kk][cb][lane][8 bf16] : 9*8*64*8 shorts = 73728 B
    __shared__ short btab[NKT * 8 * 64 * 8];
    __shared__ float scl[DIN];
    __shared__ float shf[DIN];
    __shared__ float bias2[2][HDIM];
    __shared__ float biasT[HDIM];

    const int tid = threadIdx.x;
    const int l  = tid & 63;
    const int lr = l & 15;     // edge slot within 16 (A rows / C cols)
    const int lg = l >> 4;     // k-group (A) / row-group (C)

    // ---- BN constants ----
    for (int c = tid; c < DIN; c += 256) {
        float sc = bn_gamma[c] * rsqrtf(bn_var[c] + 1e-5f);
        scl[c] = sc;
        shf[c] = bn_beta[c] - bn_mean[c] * sc;
    }
    __syncthreads();

    // ---- build B-fragment table (BN scale folded into W) ----
    for (int f = tid; f < NKT * 8 * 64; f += 256) {
        const int kk  = f >> 9;          // /(8*64)
        const int cb  = (f >> 6) & 7;
        const int ln  = f & 63;
        const int k0  = kk * 32 + (ln >> 4) * 8;
        const int col = cb * 16 + (ln & 15);
        bf16x8 bv;
        #pragma unroll
        for (int j = 0; j < 8; ++j) {
            const int k = k0 + j;
            float v = (k < DIN) ? scl[k] * W1[k * HDIM + col] : 0.f;
            bv[j] = f2bf(v);
        }
        *(bf16x8*)&btab[f * 8] = bv;
    }
    // ---- bias fold: biasT[col] = b1[col] + sum_k shf[k]*W1[k][col] ----
    {
        const int col  = tid & 127;
        const int half = tid >> 7;
        float s = 0.f;
        for (int k = half * 136; k < half * 136 + 136; ++k)
            s += shf[k] * W1[k * HDIM + col];
        bias2[half][col] = s;
    }
    __syncthreads();
    if (tid < HDIM) biasT[tid] = b1[tid] + bias2[0][tid] + bias2[1][tid];
    __syncthreads();
    // ---- after this point: NO barriers; btab/biasT are read-only ----

    float biasv[8], w2v[8];
    #pragma unroll
    for (int cb = 0; cb < 8; ++cb) {
        biasv[cb] = biasT[cb * 16 + lr];
        w2v[cb]   = W2[cb * 16 + lr];
    }
    const float b2v = b2[0];
    const bool evn = !(lr & 1);

    const int gw = blockIdx.x * 4 + (tid >> 6);
    const int NW = gridDim.x * 4;

    for (int it = gw; it < nIter; it += NW) {
        const int e0 = it * 16;
        const int pos = e0 + lr;
        const int pc  = (pos < E) ? pos : E - 1;
        const int ec  = (MODE == 2) ? eid[pc] : pc;
        const int is = index[ec];
        const int ir = index[E + ec];

        // -------- gather: 18 independent f32x4 loads, all issued up front ----
        const f32x4* ps = (const f32x4*)(x_send + (size_t)is * HDIM);
        const f32x4* pr = (const f32x4*)(x_rec  + (size_t)ir * HDIM);
        f32x4 Ls[8], Lr[8], La[2];
        #pragma unroll
        for (int kk = 0; kk < 4; ++kk) {
            Ls[kk * 2]     = ps[kk * 8 + lg * 2];
            Ls[kk * 2 + 1] = ps[kk * 8 + lg * 2 + 1];
            Lr[kk * 2]     = pr[kk * 8 + lg * 2];
            Lr[kk * 2 + 1] = pr[kk * 8 + lg * 2 + 1];
        }
        if (lg < 2) {
            const f32x4* pa = (const f32x4*)(edge_attr + (size_t)ec * INVD + lg * 8);
            La[0] = pa[0]; La[1] = pa[1];
        } else {
            La[0] = (f32x4){0.f, 0.f, 0.f, 0.f};
            La[1] = (f32x4){0.f, 0.f, 0.f, 0.f};
        }

        // -------- MFMA: 9 k-steps x 8 col-blocks --------
        f32x4 acc[8];
        #pragma unroll
        for (int cb = 0; cb < 8; ++cb) acc[cb] = (f32x4){0.f, 0.f, 0.f, 0.f};

        #pragma unroll
        for (int kk = 0; kk < NKT; ++kk) {
            f32x4 lo = (kk < 4) ? Ls[kk * 2]     : (kk < 8) ? Lr[(kk - 4) * 2]     : La[0];
            f32x4 hi = (kk < 4) ? Ls[kk * 2 + 1] : (kk < 8) ? Lr[(kk - 4) * 2 + 1] : La[1];
            bf16x8 a;
            a[0] = f2bf(lo[0]); a[1] = f2bf(lo[1]); a[2] = f2bf(lo[2]); a[3] = f2bf(lo[3]);
            a[4] = f2bf(hi[0]); a[5] = f2bf(hi[1]); a[6] = f2bf(hi[2]); a[7] = f2bf(hi[3]);
            #pragma unroll
            for (int cb = 0; cb < 8; ++cb) {
                bf16x8 b = *(const bf16x8*)&btab[((kk * 8 + cb) * 64 + l) * 8];
                acc[cb] = __builtin_amdgcn_mfma_f32_16x16x32_bf16(a, b, acc[cb], 0, 0, 0);
            }
        }

        // -------- SiLU + gate dot (16-lane reduce) --------
        float p[4] = {0.f, 0.f, 0.f, 0.f};
        #pragma unroll
        for (int cb = 0; cb < 8; ++cb) {
            #pragma unroll
            for (int q = 0; q < 4; ++q) {
                float z = acc[cb][q] + biasv[cb];
                float m = z / (1.f + __expf(-z));   // SiLU
                acc[cb][q] = m;
                p[q] += m * w2v[cb];
            }
        }
        #pragma unroll
        for (int q = 0; q < 4; ++q) {
            p[q] += __shfl_xor(p[q], 1, 64);
            p[q] += __shfl_xor(p[q], 2, 64);
            p[q] += __shfl_xor(p[q], 4, 64);
            p[q] += __shfl_xor(p[q], 8, 64);
        }

        if constexpr (MODE == 2) {
            // -------- merged gated scatter (receiver-sorted runs) --------
            float mm[8];
            int cur = -1;
            auto flushf = [&](int node) {
                #pragma unroll
                for (int c = 0; c < 4; ++c) {
                    float x0 = __shfl_xor(mm[2 * c],     1, 64);
                    float x1 = __shfl_xor(mm[2 * c + 1], 1, 64);
                    float va = evn ? mm[2 * c] : x1;
                    float vb = evn ? x0        : mm[2 * c + 1];
                    union { fp16x2 h; unsigned u; } pk;
                    pk.h = __builtin_amdgcn_cvt_pkrtz(va, vb);
                    const int col0 = evn ? (32 * c + lr) : (32 * c + 15 + lr);
                    unsigned long long a =
                        (unsigned long long)(ws + (size_t)node * HDIM + col0);
                    asm volatile("global_atomic_pk_add_f16 %0, %1, off"
                                 :: "v"(a), "v"(pk.u) : "memory");
                }
            };
            #pragma unroll
            for (int q = 0; q < 4; ++q) {
                const int row = lg * 4 + q;
                if (e0 + row < E) {                       // uniform per 16-lane group
                    const int nq = __shfl(ir, row, 64);   // receiver of that position
                    const float g = 1.f / (1.f + __expf(-(p[q] + b2v)));
                    if (nq != cur) {
                        if (cur >= 0) flushf(cur);
                        cur = nq;
                        #pragma unroll
                        for (int cb = 0; cb < 8; ++cb) mm[cb] = acc[cb][q] * g;
                    } else {
                        #pragma unroll
                        for (int cb = 0; cb < 8; ++cb) mm[cb] += acc[cb][q] * g;
                    }
                }
            }
            if (cur >= 0) flushf(cur);
        } else {
            // -------- unmerged gated scatter --------
            #pragma unroll
            for (int q = 0; q < 4; ++q) {
                const int row = lg * 4 + q;
                if (e0 + row < E) {
                    const int irq = __shfl(ir, row, 64);
                    const float g = 1.f / (1.f + __expf(-(p[q] + b2v)));
                    if constexpr (MODE == 1) {
                        float m[8];
                        #pragma unroll
                        for (int cb = 0; cb < 8; ++cb) m[cb] = acc[cb][q] * g;
                        #pragma unroll
                        for (int c = 0; c < 4; ++c) {
                            float x0 = __shfl_xor(m[2 * c],     1, 64);
                            float x1 = __shfl_xor(m[2 * c + 1], 1, 64);
                            float va = evn ? m[2 * c] : x1;
                            float vb = evn ? x0       : m[2 * c + 1];
                            union { fp16x2 h; unsigned u; } pk;
                            pk.h = __builtin_amdgcn_cvt_pkrtz(va, vb);
                            const int col0 = evn ? (32 * c + lr) : (32 * c + 15 + lr);
                            unsigned long long a =
                                (unsigned long long)(ws + (size_t)irq * HDIM + col0);
                            asm volatile("global_atomic_pk_add_f16 %0, %1, off"
                                         :: "v"(a), "v"(pk.u) : "memory");
                        }
                    } else {
                        float* orow = out + (size_t)irq * HDIM + lr;
                        #pragma unroll
                        for (int cb = 0; cb < 8; ++cb)
                            atomicAdd(orow + cb * 16, acc[cb][q] * g);
                    }
                }
            }
        }
    }
}

__global__ __launch_bounds__(256) void cvt_kernel(const __half* __restrict__ ws,
                                                  float* __restrict__ out, int n) {
    int i = (blockIdx.x * 256 + threadIdx.x) * 4;
    if (i < n) {
        const __half2* p = (const __half2*)(ws + i);
        float2 a = __half22float2(p[0]);
        float2 b = __half22float2(p[1]);
        f32x4 v = {a.x, a.y, b.x, b.y};
        *(f32x4*)(out + i) = v;
    }
}

extern "C" void kernel_launch(void* const* d_in, const int* in_sizes, int n_in,
                              void* d_out, int out_size, void* d_ws, size_t ws_size,
                              hipStream_t stream) {
    const float* x_send    = (const float*)d_in[0];
    const float* x_rec     = (const float*)d_in[1];
    const int*   index     = (const int*)d_in[2];
    const float* edge_attr = (const float*)d_in[3];
    const float* bn_gamma  = (const float*)d_in[4];
    const float* bn_beta   = (const float*)d_in[5];
    const float* bn_mean   = (const float*)d_in[6];
    const float* bn_var    = (const float*)d_in[7];
    const float* W1        = (const float*)d_in[8];
    const float* b1        = (const float*)d_in[9];
    const float* W2        = (const float*)d_in[10];
    const float* b2        = (const float*)d_in[11];
    float* out = (float*)d_out;

    const int E = in_sizes[3] / INVD;
    const int N = in_sizes[0] / HDIM;
    const int nIter = (E + 15) / 16;
    const int grid = 512;   // 2 blocks/CU (LDS-limited), barrier-free waves

    const size_t accBytes = (size_t)N * HDIM * sizeof(__half);
    const size_t accAl    = (accBytes + 255) & ~(size_t)255;
    const size_t csrBytes = ((size_t)2 * N + (size_t)E) * sizeof(int);

    if (ws_size >= accAl + csrBytes) {
        // MODE 2: CSR-sorted + merged pk-f16 atomics
        __half* ws = (__half*)d_ws;
        int* cnt = (int*)((char*)d_ws + accAl);
        int* cur = cnt + N;
        int* eid = cur + N;
        hipMemsetAsync(ws, 0, accBytes, stream);
        hipMemsetAsync(cnt, 0, (size_t)N * sizeof(int), stream);
        hist_kernel<<<(E + 255) / 256, 256, 0, stream>>>(index, cnt, E);
        scan_kernel<<<1, 1024, 0, stream>>>(cnt, cur, N);
        fill_kernel<<<(E + 255) / 256, 256, 0, stream>>>(index, cur, eid, E);
        etnn_kernel<2><<<grid, 256, 0, stream>>>(x_send, x_rec, index, edge_attr,
                                                 bn_gamma, bn_beta, bn_mean, bn_var,
                                                 W1, b1, W2, b2, eid, out, ws, E, nIter);
        const int n = N * HDIM;
        cvt_kernel<<<(n / 4 + 255) / 256, 256, 0, stream>>>(ws, out, n);
    } else if (ws_size >= accBytes) {
        // MODE 1: natural order + pk-f16 atomics (R8)
        __half* ws = (__half*)d_ws;
        hipMemsetAsync(ws, 0, accBytes, stream);
        etnn_kernel<1><<<grid, 256, 0, stream>>>(x_send, x_rec, index, edge_attr,
                                                 bn_gamma, bn_beta, bn_mean, bn_var,
                                                 W1, b1, W2, b2, nullptr, out, ws, E, nIter);
        const int n = N * HDIM;
        cvt_kernel<<<(n / 4 + 255) / 256, 256, 0, stream>>>(ws, out, n);
    } else {
        // MODE 0: scalar f32 atomics to out
        hipMemsetAsync(d_out, 0, (size_t)out_size * sizeof(float), stream);
        etnn_kernel<0><<<grid, 256, 0, stream>>>(x_send, x_rec, index, edge_attr,
                                                 bn_gamma, bn_beta, bn_mean, bn_var,
                                                 W1, b1, W2, b2, nullptr, out, nullptr, E, nIter);
    }
}

// Round 10
// 221.304 us; speedup vs baseline: 1.7200x; 1.7200x over previous
//
#include <hip/hip_runtime.h>
#include <hip/hip_bf16.h>
#include <hip/hip_fp16.h>
#include <math.h>

#define HDIM 128
#define INVD 16
#define DIN 272           // 2*H + INV
#define NKT 9             // K steps of 32 -> 288 (pad 272->288)

typedef __attribute__((ext_vector_type(4))) float f32x4;
typedef __attribute__((ext_vector_type(8))) short bf16x8;
typedef __attribute__((ext_vector_type(2))) __fp16 fp16x2;

__device__ inline short f2bf(float f) {
    union { float f; unsigned u; } v; v.f = f;
    unsigned r = v.u + 0x7FFFu + ((v.u >> 16) & 1u);   // RNE
    return (short)(r >> 16);
}

__device__ inline unsigned cvt_pk_bf16(float a, float b) {   // lo=a, hi=b, RNE
    unsigned r;
    asm("v_cvt_pk_bf16_f32 %0, %1, %2" : "=v"(r) : "v"(a), "v"(b));
    return r;
}

// Barrier-free main loop, 2-tile software pipeline: each wave owns 2x16 edges
// x 128 cols per trip; both tiles' gathers are issued before either compute,
// so tile B's HBM latency hides under tile A's MFMA+VALU work.
// W1 (BN-scale folded, bf16) pre-packed in LDS as MFMA B-fragments, read-only.
// Scatter: f16 pair packing -> global_atomic_pk_add_f16 (4 rows x 64 B/instr).
template<int MODE>   // 1 = pk-f16 to ws, 0 = scalar f32 to out (fallback)
__global__ __launch_bounds__(256, 2) void etnn_kernel(
    const float* __restrict__ x_send,
    const float* __restrict__ x_rec,
    const int*   __restrict__ index,     // [2][E] int32
    const float* __restrict__ edge_attr, // [E][16]
    const float* __restrict__ bn_gamma,
    const float* __restrict__ bn_beta,
    const float* __restrict__ bn_mean,
    const float* __restrict__ bn_var,
    const float* __restrict__ W1,        // [DIN][H]
    const float* __restrict__ b1,
    const float* __restrict__ W2,
    const float* __restrict__ b2,
    float* __restrict__ out,             // [N][H] (MODE 0)
    __half* __restrict__ ws,             // [N][H] f16 accumulator (MODE 1)
    int E, int nIter)
{
    // [kk][cb][lane][8 bf16] : 9*8*64*8 shorts = 73728 B
    __shared__ short btab[NKT * 8 * 64 * 8];
    __shared__ float scl[DIN];
    __shared__ float shf[DIN];
    __shared__ float bias2[2][HDIM];
    __shared__ float biasT[HDIM];

    const int tid = threadIdx.x;
    const int l  = tid & 63;
    const int lr = l & 15;     // edge slot within 16 (A rows / C cols)
    const int lg = l >> 4;     // k-group (A) / row-group (C)

    // ---- BN constants ----
    for (int c = tid; c < DIN; c += 256) {
        float sc = bn_gamma[c] * rsqrtf(bn_var[c] + 1e-5f);
        scl[c] = sc;
        shf[c] = bn_beta[c] - bn_mean[c] * sc;
    }
    __syncthreads();

    // ---- build B-fragment table (BN scale folded into W) ----
    for (int f = tid; f < NKT * 8 * 64; f += 256) {
        const int kk  = f >> 9;          // /(8*64)
        const int cb  = (f >> 6) & 7;
        const int ln  = f & 63;
        const int k0  = kk * 32 + (ln >> 4) * 8;
        const int col = cb * 16 + (ln & 15);
        bf16x8 bv;
        #pragma unroll
        for (int j = 0; j < 8; ++j) {
            const int k = k0 + j;
            float v = (k < DIN) ? scl[k] * W1[k * HDIM + col] : 0.f;
            bv[j] = f2bf(v);
        }
        *(bf16x8*)&btab[f * 8] = bv;
    }
    // ---- bias fold: biasT[col] = b1[col] + sum_k shf[k]*W1[k][col] ----
    {
        const int col  = tid & 127;
        const int half = tid >> 7;
        float s = 0.f;
        for (int k = half * 136; k < half * 136 + 136; ++k)
            s += shf[k] * W1[k * HDIM + col];
        bias2[half][col] = s;
    }
    __syncthreads();
    if (tid < HDIM) biasT[tid] = b1[tid] + bias2[0][tid] + bias2[1][tid];
    __syncthreads();
    // ---- after this point: NO barriers; btab/biasT are read-only ----

    float biasv[8], w2v[8];
    #pragma unroll
    for (int cb = 0; cb < 8; ++cb) {
        biasv[cb] = biasT[cb * 16 + lr];
        w2v[cb]   = W2[cb * 16 + lr];
    }
    const float b2v = b2[0];
    const bool evn = !(lr & 1);

    auto issueGather = [&](int pc, int is, int ir,
                           f32x4* Ls, f32x4* Lr, f32x4* La) {
        const f32x4* ps = (const f32x4*)(x_send + (size_t)is * HDIM);
        const f32x4* pr = (const f32x4*)(x_rec  + (size_t)ir * HDIM);
        #pragma unroll
        for (int kk = 0; kk < 4; ++kk) {
            Ls[kk * 2]     = ps[kk * 8 + lg * 2];
            Ls[kk * 2 + 1] = ps[kk * 8 + lg * 2 + 1];
            Lr[kk * 2]     = pr[kk * 8 + lg * 2];
            Lr[kk * 2 + 1] = pr[kk * 8 + lg * 2 + 1];
        }
        if (lg < 2) {
            const f32x4* pa = (const f32x4*)(edge_attr + (size_t)pc * INVD + lg * 8);
            La[0] = pa[0]; La[1] = pa[1];
        } else {
            La[0] = (f32x4){0.f, 0.f, 0.f, 0.f};
            La[1] = (f32x4){0.f, 0.f, 0.f, 0.f};
        }
    };

    auto computeTile = [&](int e0, int ir,
                           f32x4* Ls, f32x4* Lr, f32x4* La) {
        f32x4 acc[8];
        #pragma unroll
        for (int cb = 0; cb < 8; ++cb) acc[cb] = (f32x4){0.f, 0.f, 0.f, 0.f};

        #pragma unroll
        for (int kk = 0; kk < NKT; ++kk) {
            f32x4 lo = (kk < 4) ? Ls[kk * 2]     : (kk < 8) ? Lr[(kk - 4) * 2]     : La[0];
            f32x4 hi = (kk < 4) ? Ls[kk * 2 + 1] : (kk < 8) ? Lr[(kk - 4) * 2 + 1] : La[1];
            union { bf16x8 v; unsigned u[4]; } a;
            a.u[0] = cvt_pk_bf16(lo[0], lo[1]);
            a.u[1] = cvt_pk_bf16(lo[2], lo[3]);
            a.u[2] = cvt_pk_bf16(hi[0], hi[1]);
            a.u[3] = cvt_pk_bf16(hi[2], hi[3]);
            #pragma unroll
            for (int cb = 0; cb < 8; ++cb) {
                bf16x8 b = *(const bf16x8*)&btab[((kk * 8 + cb) * 64 + l) * 8];
                acc[cb] = __builtin_amdgcn_mfma_f32_16x16x32_bf16(a.v, b, acc[cb], 0, 0, 0);
            }
        }

        // SiLU + gate dot (16-lane reduce)
        float p[4] = {0.f, 0.f, 0.f, 0.f};
        #pragma unroll
        for (int cb = 0; cb < 8; ++cb) {
            #pragma unroll
            for (int q = 0; q < 4; ++q) {
                float z = acc[cb][q] + biasv[cb];
                float m = z / (1.f + __expf(-z));   // SiLU
                acc[cb][q] = m;
                p[q] += m * w2v[cb];
            }
        }
        #pragma unroll
        for (int q = 0; q < 4; ++q) {
            p[q] += __shfl_xor(p[q], 1, 64);
            p[q] += __shfl_xor(p[q], 2, 64);
            p[q] += __shfl_xor(p[q], 4, 64);
            p[q] += __shfl_xor(p[q], 8, 64);
        }

        // gated scatter
        #pragma unroll
        for (int q = 0; q < 4; ++q) {
            const int row = lg * 4 + q;
            if (e0 + row < E) {
                const int irq = __shfl(ir, row, 64);
                const float g = 1.f / (1.f + __expf(-(p[q] + b2v)));
                if constexpr (MODE == 1) {
                    float m[8];
                    #pragma unroll
                    for (int cb = 0; cb < 8; ++cb) m[cb] = acc[cb][q] * g;
                    #pragma unroll
                    for (int c = 0; c < 4; ++c) {
                        float x0 = __shfl_xor(m[2 * c],     1, 64);
                        float x1 = __shfl_xor(m[2 * c + 1], 1, 64);
                        float va = evn ? m[2 * c] : x1;
                        float vb = evn ? x0       : m[2 * c + 1];
                        union { fp16x2 h; unsigned u; } pk;
                        pk.h = __builtin_amdgcn_cvt_pkrtz(va, vb);
                        const int col0 = evn ? (32 * c + lr) : (32 * c + 15 + lr);
                        unsigned long long a =
                            (unsigned long long)(ws + (size_t)irq * HDIM + col0);
                        asm volatile("global_atomic_pk_add_f16 %0, %1, off"
                                     :: "v"(a), "v"(pk.u) : "memory");
                    }
                } else {
                    float* orow = out + (size_t)irq * HDIM + lr;
                    #pragma unroll
                    for (int cb = 0; cb < 8; ++cb)
                        atomicAdd(orow + cb * 16, acc[cb][q] * g);
                }
            }
        }
    };

    const int gw = blockIdx.x * 4 + (tid >> 6);
    const int NW = gridDim.x * 4;

    for (int it = gw; it < nIter; it += 2 * NW) {
        const int itB  = it + NW;
        const bool hasB = itB < nIter;          // wave-uniform

        // ---- tile A indices ----
        const int posA = it * 16 + lr;
        const int pcA  = (posA < E) ? posA : E - 1;
        const int isA  = index[pcA];
        const int irA  = index[E + pcA];

        // ---- tile B indices ----
        int pcB = 0, isB = 0, irB = 0;
        if (hasB) {
            const int posB = itB * 16 + lr;
            pcB = (posB < E) ? posB : E - 1;
            isB = index[pcB];
            irB = index[E + pcB];
        }

        // ---- issue both tiles' gathers (36 f32x4 in flight) ----
        f32x4 LsA[8], LrA[8], LaA[2];
        f32x4 LsB[8], LrB[8], LaB[2];
        issueGather(pcA, isA, irA, LsA, LrA, LaA);
        if (hasB) issueGather(pcB, isB, irB, LsB, LrB, LaB);

        // ---- compute A (B's loads hide under this), then B ----
        computeTile(it * 16, irA, LsA, LrA, LaA);
        if (hasB) computeTile(itB * 16, irB, LsB, LrB, LaB);
    }
}

__global__ __launch_bounds__(256) void cvt_kernel(const __half* __restrict__ ws,
                                                  float* __restrict__ out, int n) {
    int i = (blockIdx.x * 256 + threadIdx.x) * 4;
    if (i < n) {
        const __half2* p = (const __half2*)(ws + i);
        float2 a = __half22float2(p[0]);
        float2 b = __half22float2(p[1]);
        f32x4 v = {a.x, a.y, b.x, b.y};
        *(f32x4*)(out + i) = v;
    }
}

extern "C" void kernel_launch(void* const* d_in, const int* in_sizes, int n_in,
                              void* d_out, int out_size, void* d_ws, size_t ws_size,
                              hipStream_t stream) {
    const float* x_send    = (const float*)d_in[0];
    const float* x_rec     = (const float*)d_in[1];
    const int*   index     = (const int*)d_in[2];
    const float* edge_attr = (const float*)d_in[3];
    const float* bn_gamma  = (const float*)d_in[4];
    const float* bn_beta   = (const float*)d_in[5];
    const float* bn_mean   = (const float*)d_in[6];
    const float* bn_var    = (const float*)d_in[7];
    const float* W1        = (const float*)d_in[8];
    const float* b1        = (const float*)d_in[9];
    const float* W2        = (const float*)d_in[10];
    const float* b2        = (const float*)d_in[11];
    float* out = (float*)d_out;

    const int E = in_sizes[3] / INVD;
    const int N = in_sizes[0] / HDIM;
    const int nIter = (E + 15) / 16;
    const int grid = 512;   // 2 blocks/CU (LDS-limited), barrier-free waves

    const size_t accBytes = (size_t)N * HDIM * sizeof(__half);
    if (ws_size >= accBytes) {
        __half* ws = (__half*)d_ws;
        hipMemsetAsync(ws, 0, accBytes, stream);
        etnn_kernel<1><<<grid, 256, 0, stream>>>(x_send, x_rec, index, edge_attr,
                                                 bn_gamma, bn_beta, bn_mean, bn_var,
                                                 W1, b1, W2, b2, out, ws, E, nIter);
        const int n = N * HDIM;
        cvt_kernel<<<(n / 4 + 255) / 256, 256, 0, stream>>>(ws, out, n);
    } else {
        hipMemsetAsync(d_out, 0, (size_t)out_size * sizeof(float), stream);
        etnn_kernel<0><<<grid, 256, 0, stream>>>(x_send, x_rec, index, edge_attr,
                                                 bn_gamma, bn_beta, bn_mean, bn_var,
                                                 W1, b1, W2, b2, out, nullptr, E, nIter);
    }
}

// Round 11
// 198.574 us; speedup vs baseline: 1.9168x; 1.1145x over previous
//
#include <hip/hip_runtime.h>
#include <hip/hip_bf16.h>
#include <hip/hip_fp16.h>
#include <math.h>

#define HDIM 128
#define INVD 16
#define DIN 272           // 2*H + INV
#define NKT 9             // K steps of 32 -> 288 (pad 272->288)

typedef __attribute__((ext_vector_type(4))) float f32x4;
typedef __attribute__((ext_vector_type(8))) short bf16x8;
typedef __attribute__((ext_vector_type(2))) __fp16 fp16x2;

__device__ inline short f2bf(float f) {
    union { float f; unsigned u; } v; v.f = f;
    unsigned r = v.u + 0x7FFFu + ((v.u >> 16) & 1u);   // RNE
    return (short)(r >> 16);
}

__device__ inline unsigned cvt_pk_bf16(float a, float b) {   // lo=a, hi=b, RNE
    unsigned r;
    asm("v_cvt_pk_bf16_f32 %0, %1, %2" : "=v"(r) : "v"(a), "v"(b));
    return r;
}

__device__ inline float fast_rcp(float x) {                  // v_rcp_f32, ~1ulp
    float r;
    asm("v_rcp_f32 %0, %1" : "=v"(r) : "v"(x));
    return r;
}

// Barrier-free main loop; explicit 2-deep software pipeline pinned with
// sched_barrier(0): tile(i+1)'s 18 gather loads are issued BEFORE tile(i)'s
// compute and held live across it (dual register buffers, static indexing).
// W1 (BN-scale folded, bf16) pre-packed in LDS as MFMA B-fragments, read-only.
template<int MODE>   // 1 = pk-f16 to ws, 0 = scalar f32 to out (fallback)
__global__ __launch_bounds__(256, 2) void etnn_kernel(
    const float* __restrict__ x_send,
    const float* __restrict__ x_rec,
    const int*   __restrict__ index,     // [2][E] int32
    const float* __restrict__ edge_attr, // [E][16]
    const float* __restrict__ bn_gamma,
    const float* __restrict__ bn_beta,
    const float* __restrict__ bn_mean,
    const float* __restrict__ bn_var,
    const float* __restrict__ W1,        // [DIN][H]
    const float* __restrict__ b1,
    const float* __restrict__ W2,
    const float* __restrict__ b2,
    float* __restrict__ out,             // [N][H] (MODE 0)
    __half* __restrict__ ws,             // [N][H] f16 accumulator (MODE 1)
    int E, int nIter)
{
    __shared__ short btab[NKT * 8 * 64 * 8];   // 73728 B
    __shared__ float scl[DIN];
    __shared__ float shf[DIN];
    __shared__ float bias2[2][HDIM];
    __shared__ float biasT[HDIM];

    const int tid = threadIdx.x;
    const int l  = tid & 63;
    const int lr = l & 15;     // edge slot within 16
    const int lg = l >> 4;     // k-group / row-group

    for (int c = tid; c < DIN; c += 256) {
        float sc = bn_gamma[c] * rsqrtf(bn_var[c] + 1e-5f);
        scl[c] = sc;
        shf[c] = bn_beta[c] - bn_mean[c] * sc;
    }
    __syncthreads();

    for (int f = tid; f < NKT * 8 * 64; f += 256) {
        const int kk  = f >> 9;
        const int cb  = (f >> 6) & 7;
        const int ln  = f & 63;
        const int k0  = kk * 32 + (ln >> 4) * 8;
        const int col = cb * 16 + (ln & 15);
        bf16x8 bv;
        #pragma unroll
        for (int j = 0; j < 8; ++j) {
            const int k = k0 + j;
            float v = (k < DIN) ? scl[k] * W1[k * HDIM + col] : 0.f;
            bv[j] = f2bf(v);
        }
        *(bf16x8*)&btab[f * 8] = bv;
    }
    {
        const int col  = tid & 127;
        const int half = tid >> 7;
        float s = 0.f;
        for (int k = half * 136; k < half * 136 + 136; ++k)
            s += shf[k] * W1[k * HDIM + col];
        bias2[half][col] = s;
    }
    __syncthreads();
    if (tid < HDIM) biasT[tid] = b1[tid] + bias2[0][tid] + bias2[1][tid];
    __syncthreads();
    // ---- NO barriers below; btab/biasT read-only ----

    float biasv[8], w2v[8];
    #pragma unroll
    for (int cb = 0; cb < 8; ++cb) {
        biasv[cb] = biasT[cb * 16 + lr];
        w2v[cb]   = W2[cb * 16 + lr];
    }
    const float b2v = b2[0];
    const bool evn = !(lr & 1);

    const int gw = blockIdx.x * 4 + (tid >> 6);
    const int NW = gridDim.x * 4;

    // clamped index fetch for tile `itx`
    auto ldIdx = [&](int itx, int& pc, int& is, int& ir) {
        int pos = itx * 16 + lr;
        pc = (pos < E) ? pos : E - 1;
        if (pc < 0) pc = 0;
        is = index[pc];
        ir = index[E + pc];
    };

    auto issueGather = [&](int pc, int is, int ir,
                           f32x4* Ls, f32x4* Lr, f32x4* La) {
        const f32x4* ps = (const f32x4*)(x_send + (size_t)is * HDIM);
        const f32x4* pr = (const f32x4*)(x_rec  + (size_t)ir * HDIM);
        #pragma unroll
        for (int kk = 0; kk < 4; ++kk) {
            Ls[kk * 2]     = ps[kk * 8 + lg * 2];
            Ls[kk * 2 + 1] = ps[kk * 8 + lg * 2 + 1];
            Lr[kk * 2]     = pr[kk * 8 + lg * 2];
            Lr[kk * 2 + 1] = pr[kk * 8 + lg * 2 + 1];
        }
        if (lg < 2) {
            const f32x4* pa = (const f32x4*)(edge_attr + (size_t)pc * INVD + lg * 8);
            La[0] = pa[0]; La[1] = pa[1];
        } else {
            La[0] = (f32x4){0.f, 0.f, 0.f, 0.f};
            La[1] = (f32x4){0.f, 0.f, 0.f, 0.f};
        }
    };

    auto computeTile = [&](int e0, int ir,
                           f32x4* Ls, f32x4* Lr, f32x4* La) {
        f32x4 acc[8];
        #pragma unroll
        for (int cb = 0; cb < 8; ++cb) acc[cb] = (f32x4){0.f, 0.f, 0.f, 0.f};

        #pragma unroll
        for (int kk = 0; kk < NKT; ++kk) {
            f32x4 lo = (kk < 4) ? Ls[kk * 2]     : (kk < 8) ? Lr[(kk - 4) * 2]     : La[0];
            f32x4 hi = (kk < 4) ? Ls[kk * 2 + 1] : (kk < 8) ? Lr[(kk - 4) * 2 + 1] : La[1];
            union { bf16x8 v; unsigned u[4]; } a;
            a.u[0] = cvt_pk_bf16(lo[0], lo[1]);
            a.u[1] = cvt_pk_bf16(lo[2], lo[3]);
            a.u[2] = cvt_pk_bf16(hi[0], hi[1]);
            a.u[3] = cvt_pk_bf16(hi[2], hi[3]);
            #pragma unroll
            for (int cb = 0; cb < 8; ++cb) {
                bf16x8 b = *(const bf16x8*)&btab[((kk * 8 + cb) * 64 + l) * 8];
                acc[cb] = __builtin_amdgcn_mfma_f32_16x16x32_bf16(a.v, b, acc[cb], 0, 0, 0);
            }
        }

        // SiLU + gate dot (16-lane reduce); rcp-based (no slow f32 division)
        float p[4] = {0.f, 0.f, 0.f, 0.f};
        #pragma unroll
        for (int cb = 0; cb < 8; ++cb) {
            #pragma unroll
            for (int q = 0; q < 4; ++q) {
                float z = acc[cb][q] + biasv[cb];
                float m = z * fast_rcp(1.f + __expf(-z));   // SiLU
                acc[cb][q] = m;
                p[q] += m * w2v[cb];
            }
        }
        #pragma unroll
        for (int q = 0; q < 4; ++q) {
            p[q] += __shfl_xor(p[q], 1, 64);
            p[q] += __shfl_xor(p[q], 2, 64);
            p[q] += __shfl_xor(p[q], 4, 64);
            p[q] += __shfl_xor(p[q], 8, 64);
        }

        #pragma unroll
        for (int q = 0; q < 4; ++q) {
            const int row = lg * 4 + q;
            if (e0 + row < E) {
                const int irq = __shfl(ir, row, 64);
                const float g = fast_rcp(1.f + __expf(-(p[q] + b2v)));
                if constexpr (MODE == 1) {
                    float m[8];
                    #pragma unroll
                    for (int cb = 0; cb < 8; ++cb) m[cb] = acc[cb][q] * g;
                    #pragma unroll
                    for (int c = 0; c < 4; ++c) {
                        float x0 = __shfl_xor(m[2 * c],     1, 64);
                        float x1 = __shfl_xor(m[2 * c + 1], 1, 64);
                        float va = evn ? m[2 * c] : x1;
                        float vb = evn ? x0       : m[2 * c + 1];
                        union { fp16x2 h; unsigned u; } pk;
                        pk.h = __builtin_amdgcn_cvt_pkrtz(va, vb);
                        const int col0 = evn ? (32 * c + lr) : (32 * c + 15 + lr);
                        unsigned long long a =
                            (unsigned long long)(ws + (size_t)irq * HDIM + col0);
                        asm volatile("global_atomic_pk_add_f16 %0, %1, off"
                                     :: "v"(a), "v"(pk.u) : "memory");
                    }
                } else {
                    float* orow = out + (size_t)irq * HDIM + lr;
                    #pragma unroll
                    for (int cb = 0; cb < 8; ++cb)
                        atomicAdd(orow + cb * 16, acc[cb][q] * g);
                }
            }
        }
    };

    // ---------- 2-deep pipelined main loop ----------
    f32x4 LsA[8], LrA[8], LaA[2];
    f32x4 LsB[8], LrB[8], LaB[2];

    if (gw >= nIter) return;

    int pc0, is0, ir0;                 // idx of tile resident in bufA
    int pc1, is1, ir1;                 // idx of next tile (gather not yet issued)
    ldIdx(gw, pc0, is0, ir0);
    issueGather(pc0, is0, ir0, LsA, LrA, LaA);
    ldIdx(gw + NW, pc1, is1, ir1);

    for (int it = gw; it < nIter; it += 2 * NW) {
        // ---- phase A: prefetch tile(it+NW) into bufB, then compute bufA ----
        issueGather(pc1, is1, ir1, LsB, LrB, LaB);
        int pc2, is2, ir2;
        ldIdx(it + 2 * NW, pc2, is2, ir2);
        __builtin_amdgcn_sched_barrier(0);   // pin prefetch above compute
        computeTile(it * 16, ir0, LsA, LrA, LaA);

        // ---- phase B: prefetch tile(it+2NW) into bufA, then compute bufB ----
        issueGather(pc2, is2, ir2, LsA, LrA, LaA);
        int pc3, is3, ir3;
        ldIdx(it + 3 * NW, pc3, is3, ir3);
        __builtin_amdgcn_sched_barrier(0);
        if (it + NW < nIter)
            computeTile((it + NW) * 16, ir1, LsB, LrB, LaB);

        pc0 = pc2; is0 = is2; ir0 = ir2;
        pc1 = pc3; is1 = is3; ir1 = ir3;
    }
}

__global__ __launch_bounds__(256) void cvt_kernel(const __half* __restrict__ ws,
                                                  float* __restrict__ out, int n) {
    int i = (blockIdx.x * 256 + threadIdx.x) * 4;
    if (i < n) {
        const __half2* p = (const __half2*)(ws + i);
        float2 a = __half22float2(p[0]);
        float2 b = __half22float2(p[1]);
        f32x4 v = {a.x, a.y, b.x, b.y};
        *(f32x4*)(out + i) = v;
    }
}

extern "C" void kernel_launch(void* const* d_in, const int* in_sizes, int n_in,
                              void* d_out, int out_size, void* d_ws, size_t ws_size,
                              hipStream_t stream) {
    const float* x_send    = (const float*)d_in[0];
    const float* x_rec     = (const float*)d_in[1];
    const int*   index     = (const int*)d_in[2];
    const float* edge_attr = (const float*)d_in[3];
    const float* bn_gamma  = (const float*)d_in[4];
    const float* bn_beta   = (const float*)d_in[5];
    const float* bn_mean   = (const float*)d_in[6];
    const float* bn_var    = (const float*)d_in[7];
    const float* W1        = (const float*)d_in[8];
    const float* b1        = (const float*)d_in[9];
    const float* W2        = (const float*)d_in[10];
    const float* b2        = (const float*)d_in[11];
    float* out = (float*)d_out;

    const int E = in_sizes[3] / INVD;
    const int N = in_sizes[0] / HDIM;
    const int nIter = (E + 15) / 16;
    const int grid = 512;   // 2 blocks/CU (LDS-limited), barrier-free waves

    const size_t accBytes = (size_t)N * HDIM * sizeof(__half);
    if (ws_size >= accBytes) {
        __half* ws = (__half*)d_ws;
        hipMemsetAsync(ws, 0, accBytes, stream);
        etnn_kernel<1><<<grid, 256, 0, stream>>>(x_send, x_rec, index, edge_attr,
                                                 bn_gamma, bn_beta, bn_mean, bn_var,
                                                 W1, b1, W2, b2, out, ws, E, nIter);
        const int n = N * HDIM;
        cvt_kernel<<<(n / 4 + 255) / 256, 256, 0, stream>>>(ws, out, n);
    } else {
        hipMemsetAsync(d_out, 0, (size_t)out_size * sizeof(float), stream);
        etnn_kernel<0><<<grid, 256, 0, stream>>>(x_send, x_rec, index, edge_attr,
                                                 bn_gamma, bn_beta, bn_mean, bn_var,
                                                 W1, b1, W2, b2, out, nullptr, E, nIter);
    }
}